// Round 3
// baseline (206.849 us; speedup 1.0000x reference)
//
#include <hip/hip_runtime.h>

#define S_LEN 2048
#define NBATCH 32

typedef __bf16 bf16x8 __attribute__((ext_vector_type(8)));
typedef float f32x4 __attribute__((ext_vector_type(4)));
typedef unsigned short bf_t;   // bf16 storage

__device__ __forceinline__ unsigned short f2bf(float f) {
  __bf16 h = (__bf16)f;
  return __builtin_bit_cast(unsigned short, h);
}

#if __has_builtin(__builtin_amdgcn_global_load_lds)
#define USE_GLL 1
#else
#define USE_GLL 0
#endif

// async global->LDS, 16B per lane. ldsbase must be wave-uniform (HW adds lane*16).
__device__ __forceinline__ void load_lds16(const void* g, void* ldsbase) {
#if USE_GLL
  __builtin_amdgcn_global_load_lds(
      (const __attribute__((address_space(1))) unsigned int*)g,
      (__attribute__((address_space(3))) unsigned int*)ldsbase, 16, 0, 0);
#endif
}

// ---------------------------------------------------------------------------
// x fp32 [B,S,128] -> bf16, 8 elems/thread
__global__ void convert_x(const float* __restrict__ x, bf_t* __restrict__ xb) {
  const size_t i = (size_t)blockIdx.x * blockDim.x + threadIdx.x; // 0..1048575
  const float4 a = ((const float4*)x)[2 * i];
  const float4 c = ((const float4*)x)[2 * i + 1];
  ushort4 o0; o0.x = f2bf(a.x); o0.y = f2bf(a.y); o0.z = f2bf(a.z); o0.w = f2bf(a.w);
  ushort4 o1; o1.x = f2bf(c.x); o1.y = f2bf(c.y); o1.z = f2bf(c.z); o1.w = f2bf(c.w);
  ((ushort4*)xb)[2 * i] = o0;
  ((ushort4*)xb)[2 * i + 1] = o1;
}

// fold conv-bias + BN into per-channel alpha/bias (two layers)
__global__ void fold_bn(const float* __restrict__ b1, const float* __restrict__ g1,
                        const float* __restrict__ be1, const float* __restrict__ m1,
                        const float* __restrict__ v1,
                        const float* __restrict__ b2, const float* __restrict__ g2,
                        const float* __restrict__ be2, const float* __restrict__ m2,
                        const float* __restrict__ v2, float* __restrict__ abuf) {
  int c = threadIdx.x;
  if (c < 256) {
    float a1 = g1[c] * rsqrtf(v1[c] + 1e-5f);
    abuf[c] = a1;
    abuf[256 + c] = (b1[c] - m1[c]) * a1 + be1[c];
    float a2 = g2[c] * rsqrtf(v2[c] + 1e-5f);
    abuf[512 + c] = a2;
    abuf[768 + c] = (b2[c] - m2[c]) * a2 + be2[c];
  }
}

// Weights [Cout,Cin,TAPS] fp32 -> fragment-major bf16:
// wfm[g][t][f][l][j], g=co-block-of-64, t = (cc*TAPS+k)*4+q,
// co = g*64 + f*16 + (l&15), ci = cc*128 + q*32 + (l>>4)*8 + j, tap = k.
template <int CIN, int COUT, int TAPS>
__global__ void prep_w(const float* __restrict__ w, bf_t* __restrict__ wfm) {
  constexpr int T = CIN * TAPS / 32;
  const int idx = blockIdx.x * 256 + threadIdx.x;
  constexpr int total = COUT * CIN * TAPS;
  if (idx >= total) return;
  const int j = idx & 7;
  const int l = (idx >> 3) & 63;
  const int f = (idx >> 9) & 3;
  const int gt = idx >> 11;
  const int t = gt % T;
  const int g = gt / T;
  const int co = g * 64 + f * 16 + (l & 15);
  const int cc = t / (TAPS * 4);
  const int k = (t / 4) % TAPS;
  const int q = t & 3;
  const int ci = cc * 128 + q * 32 + (l >> 4) * 8 + j;
  wfm[idx] = f2bf(w[((size_t)co * CIN + ci) * TAPS + k]);
}

// ---------------------------------------------------------------------------
// Fused conv1d(K=TAPS, pad) + BN + ReLU, bf16 MFMA implicit GEMM.
// Block: 256 thr = 4 waves (2 co x 2 pos). Block tile: 128co x 128pos, NT
// position-tiles per block, double-buffered LDS, stage-ahead pipeline
// (T3-minimum: one vmcnt(0)+barrier per chunk, issued a full chunk early).
// Wave: 64co x 64pos, acc[4][4]. A-frags from L2, depth-4 rotating prefetch.
// LDS x-tile [NROWS][128ci] bf16, XOR-swizzled (row&7)<<4.
template <int CIN, int COUT, int TAPS, int NT>
__global__ __launch_bounds__(256, 2)
void conv_bn_relu(const bf_t* __restrict__ xin, const bf_t* __restrict__ wfm,
                  const float* __restrict__ alpha, const float* __restrict__ bias,
                  bf_t* __restrict__ hout) {
  constexpr int CC = CIN / 128;
  constexpr int HALO = (TAPS - 1) / 2;
  constexpr int NROWS = 128 + 2 * HALO;
  constexpr int TCC = TAPS * 4;     // K-steps per 128-ci slice (%4 == 0)
  constexpr int T = CC * TCC;
  constexpr int NCH = NT * CC;      // chunks per block
  constexpr int SLICE = NROWS * 256;

  __shared__ char smem[2 * SLICE];

  const int tid = threadIdx.x;
  const int l = tid & 63;
  const int wv = tid >> 6;   // 0..3
  const int wr = wv >> 1;    // 0..1 : co-group of 64
  const int wn = wv & 1;     // 0..1 : pos-group of 64
  const int nb = blockIdx.x;
  const int mb = nb & 1;                 // co-half of 128
  const int rest = nb >> 1;
  const int b = rest / (16 / NT);
  const int stb = (rest % (16 / NT)) * NT;
  const int l15 = l & 15;
  const int l4 = l >> 4;

  f32x4 acc[4][4] = {};
  const bf_t* wbase = wfm + (size_t)(mb * 2 + wr) * (T * 2048);
  const char* xbase = (const char*)xin;

  auto STAGE = [&](int bufsel, int s0t, int cc) {
    const char* src = xbase + ((size_t)b * S_LEN * CIN + cc * 128) * 2;
    char* sb = smem + bufsel * SLICE;
    for (int off = tid * 16; off < SLICE; off += 256 * 16) {
      const int row = off >> 8;
      const int c = off & 255;
      const int s = s0t - HALO + row;
      const int cs = c ^ ((row & 7) << 4);
      void* ldsbase = (void*)(sb + (off - l * 16)); // wave-uniform
      if ((unsigned)s < (unsigned)S_LEN) {
#if USE_GLL
        load_lds16(src + (size_t)s * (CIN * 2) + cs, ldsbase);
#else
        *(int4*)(sb + off) = *(const int4*)(src + (size_t)s * (CIN * 2) + cs);
#endif
      } else {
        *(int4*)(sb + off) = make_int4(0, 0, 0, 0);
      }
    }
  };

  // ---- prologue: stage chunk 0, preload A steps 0..3 of slice 0
  bf16x8 apf[4][4];
  STAGE(0, stb << 7, 0);
#pragma unroll
  for (int pt = 0; pt < 4; ++pt)
#pragma unroll
    for (int f = 0; f < 4; ++f)
      apf[pt][f] = *(const bf16x8*)(wbase + ((size_t)(pt * 4 + f) * 64 + l) * 8);
  __syncthreads();

#pragma unroll 1
  for (int c = 0; c < NCH; ++c) {
    const int t = c / CC;
    const int cc = c % CC;
    const int s0 = (stb + t) << 7;
    char* sb = smem + (c & 1) * SLICE;
    const bool more = (c + 1 < NCH);
    if (more) STAGE((c + 1) & 1, (stb + (c + 1) / CC) << 7, (c + 1) % CC);
    const int ccn = (c + 1) % CC;  // next chunk's slice (valid when more)

#pragma unroll
    for (int tl = 0; tl < TCC; ++tl) {
      const int k = tl >> 2;
      const int q = tl & 3;
      bf16x8 bfr[4];
#pragma unroll
      for (int fn = 0; fn < 4; ++fn) {
        const int row = wn * 64 + fn * 16 + l15 + k;
        const int cb = q * 64 + l4 * 16;
        bfr[fn] = *(const bf16x8*)(sb + row * 256 + (cb ^ ((row & 7) << 4)));
      }
#pragma unroll
      for (int f = 0; f < 4; ++f)
#pragma unroll
        for (int n = 0; n < 4; ++n)
          acc[f][n] = __builtin_amdgcn_mfma_f32_16x16x32_bf16(
              apf[tl & 3][f], bfr[n], acc[f][n], 0, 0, 0);
      // depth-4 A prefetch (wraps into next chunk's slice)
      if (tl + 4 < TCC) {
#pragma unroll
        for (int f = 0; f < 4; ++f)
          apf[tl & 3][f] = *(const bf16x8*)(wbase +
              ((size_t)((cc * TCC + tl + 4) * 4 + f) * 64 + l) * 8);
      } else if (more) {
#pragma unroll
        for (int f = 0; f < 4; ++f)
          apf[tl & 3][f] = *(const bf16x8*)(wbase +
              ((size_t)((ccn * TCC + (tl + 4 - TCC)) * 4 + f) * 64 + l) * 8);
      }
    }
    __syncthreads();

    if (cc == CC - 1) {
      // ---- epilogue for this tile: y = relu(acc*alpha + bias) -> bf16
      const int cobase = mb * 128 + wr * 64;
#pragma unroll
      for (int f = 0; f < 4; ++f) {
        const int co0 = cobase + f * 16 + l4 * 4;
        const f32x4 al = *(const f32x4*)(alpha + co0);
        const f32x4 bi = *(const f32x4*)(bias + co0);
#pragma unroll
        for (int n = 0; n < 4; ++n) {
          const int s = s0 + wn * 64 + n * 16 + l15;
          ushort4 pk;
          pk.x = f2bf(fmaxf(acc[f][n][0] * al[0] + bi[0], 0.f));
          pk.y = f2bf(fmaxf(acc[f][n][1] * al[1] + bi[1], 0.f));
          pk.z = f2bf(fmaxf(acc[f][n][2] * al[2] + bi[2], 0.f));
          pk.w = f2bf(fmaxf(acc[f][n][3] * al[3] + bi[3], 0.f));
          *(ushort4*)((char*)hout + ((size_t)(b * S_LEN + s) * COUT + co0) * 2) = pk;
          acc[f][n][0] = 0.f; acc[f][n][1] = 0.f;
          acc[f][n][2] = 0.f; acc[f][n][3] = 0.f;
        }
      }
    }
  }
}

// ---------------------------------------------------------------------------
// Final 1x1 conv (256->128) + bias + masked sum-pool -> partials [B][16][128]
__global__ __launch_bounds__(512, 4)
void conv_pool(const bf_t* __restrict__ xin, const bf_t* __restrict__ wfm,
               const float* __restrict__ bfin, const int* __restrict__ spi,
               float* __restrict__ gpart) {
  constexpr int CIN = 256;
  constexpr int T = 8;

  __shared__ char smem[128 * 256];
  __shared__ float red[4][128];

  const int tid = threadIdx.x;
  const int l = tid & 63;
  const int wv = tid >> 6;
  const int wr = wv >> 2;
  const int wn = wv & 3;
  const int nb = blockIdx.x;
  const int b = nb >> 4;
  const int st = nb & 15;
  const int s0 = st << 7;
  const int l15 = l & 15;
  const int l4 = l >> 4;

  f32x4 acc[4][2] = {};
  const bf_t* wbase = wfm + (size_t)wr * (T * 2048);

  for (int cc = 0; cc < 2; ++cc) {
    const char* src = (const char*)xin + ((size_t)b * S_LEN * CIN + cc * 128) * 2;
    for (int off = tid * 16; off < 128 * 256; off += 512 * 16) {
      const int row = off >> 8;
      const int c = off & 255;
      const int cs = c ^ ((row & 7) << 4);
      void* ldsbase = (void*)(smem + (off - l * 16));
#if USE_GLL
      load_lds16(src + (size_t)(s0 + row) * (CIN * 2) + cs, ldsbase);
#else
      *(int4*)(smem + off) = *(const int4*)(src + (size_t)(s0 + row) * (CIN * 2) + cs);
#endif
    }
    __syncthreads();

#pragma unroll
    for (int q = 0; q < 4; ++q) {
      const int t = cc * 4 + q;
      bf16x8 bfr[2];
#pragma unroll
      for (int fn = 0; fn < 2; ++fn) {
        const int row = wn * 32 + fn * 16 + l15;
        const int cb = q * 64 + l4 * 16;
        bfr[fn] = *(const bf16x8*)(smem + row * 256 + (cb ^ ((row & 7) << 4)));
      }
#pragma unroll
      for (int f = 0; f < 4; ++f) {
        const bf16x8 afr =
            *(const bf16x8*)(wbase + ((size_t)(t * 4 + f) * 64 + l) * 8);
        acc[f][0] = __builtin_amdgcn_mfma_f32_16x16x32_bf16(afr, bfr[0], acc[f][0], 0, 0, 0);
        acc[f][1] = __builtin_amdgcn_mfma_f32_16x16x32_bf16(afr, bfr[1], acc[f][1], 0, 0, 0);
      }
    }
    __syncthreads();
  }

  int len = spi[b];
  if (len < 0) len = S_LEN;

#pragma unroll
  for (int f = 0; f < 4; ++f) {
    const int co0 = wr * 64 + f * 16 + l4 * 4;
    const f32x4 bi = *(const f32x4*)(bfin + co0);
    f32x4 vs = {};
#pragma unroll
    for (int fn = 0; fn < 2; ++fn) {
      const int s = s0 + wn * 32 + fn * 16 + l15;
      const float m = (s < len) ? 1.f : 0.f;
      vs[0] += (acc[f][fn][0] + bi[0]) * m;
      vs[1] += (acc[f][fn][1] + bi[1]) * m;
      vs[2] += (acc[f][fn][2] + bi[2]) * m;
      vs[3] += (acc[f][fn][3] + bi[3]) * m;
    }
#pragma unroll
    for (int d = 1; d < 16; d <<= 1) {
      vs[0] += __shfl_xor(vs[0], d, 64);
      vs[1] += __shfl_xor(vs[1], d, 64);
      vs[2] += __shfl_xor(vs[2], d, 64);
      vs[3] += __shfl_xor(vs[3], d, 64);
    }
    if (l15 == 0) {
      red[wn][co0 + 0] = vs[0];
      red[wn][co0 + 1] = vs[1];
      red[wn][co0 + 2] = vs[2];
      red[wn][co0 + 3] = vs[3];
    }
  }
  __syncthreads();
  if (tid < 128) {
    float p = red[0][tid] + red[1][tid] + red[2][tid] + red[3][tid];
    gpart[((size_t)b * 16 + st) * 128 + tid] = p;
  }
}

// pooled[b][d] = sum(partials) / max(len,1)
__global__ void finalize(const float* __restrict__ gpart, const int* __restrict__ spi,
                         float* __restrict__ out) {
  const int b = blockIdx.x;
  const int d = threadIdx.x;
  float s = 0.f;
#pragma unroll
  for (int t = 0; t < 16; ++t) s += gpart[((size_t)b * 16 + t) * 128 + d];
  int len = spi[b];
  if (len < 0) len = S_LEN;
  float denom = (float)(len < 1 ? 1 : len);
  out[b * 128 + d] = s / denom;
}

// ---------------------------------------------------------------------------
extern "C" void kernel_launch(void* const* d_in, const int* in_sizes, int n_in,
                              void* d_out, int out_size, void* d_ws, size_t ws_size,
                              hipStream_t stream) {
  (void)in_sizes; (void)n_in; (void)out_size; (void)ws_size;
  const float* x = (const float*)d_in[0];
  const int* spi = (const int*)d_in[1];
  const float* W1 = (const float*)d_in[2];
  const float* b1 = (const float*)d_in[3];
  const float* g1 = (const float*)d_in[4];
  const float* be1 = (const float*)d_in[5];
  const float* m1 = (const float*)d_in[6];
  const float* v1 = (const float*)d_in[7];
  const float* W2 = (const float*)d_in[8];
  const float* b2 = (const float*)d_in[9];
  const float* g2 = (const float*)d_in[10];
  const float* be2 = (const float*)d_in[11];
  const float* m2 = (const float*)d_in[12];
  const float* v2 = (const float*)d_in[13];
  const float* Wf = (const float*)d_in[14];
  const float* bf_ = (const float*)d_in[15];
  float* out = (float*)d_out;

  char* ws = (char*)d_ws;
  bf_t* xb   = (bf_t*)(ws);                          // 16,777,216 B
  bf_t* h1   = (bf_t*)(ws + 16777216);               // 33,554,432 B
  bf_t* h2   = (bf_t*)(ws + 50331648);               // 33,554,432 B
  bf_t* wf1  = (bf_t*)(ws + 83886080);               //    327,680 B
  bf_t* wf2  = (bf_t*)(ws + 84213760);               //    655,360 B
  bf_t* wff  = (bf_t*)(ws + 84869120);               //     65,536 B
  float* abuf  = (float*)(ws + 84934656);            //      4,096 B
  float* gpart = (float*)(ws + 84938752);            //    262,144 B

  convert_x<<<4096, 256, 0, stream>>>(x, xb);
  fold_bn<<<1, 256, 0, stream>>>(b1, g1, be1, m1, v1, b2, g2, be2, m2, v2, abuf);
  prep_w<128, 256, 5><<<640, 256, 0, stream>>>(W1, wf1);
  prep_w<256, 256, 5><<<1280, 256, 0, stream>>>(W2, wf2);
  prep_w<256, 128, 1><<<128, 256, 0, stream>>>(Wf, wff);

  conv_bn_relu<128, 256, 5, 2><<<512, 256, 0, stream>>>(xb, wf1, abuf, abuf + 256, h1);
  conv_bn_relu<256, 256, 5, 2><<<512, 256, 0, stream>>>(h1, wf2, abuf + 512, abuf + 768, h2);
  conv_pool<<<512, 512, 0, stream>>>(h2, wff, bf_, spi, gpart);
  finalize<<<32, 128, 0, stream>>>(gpart, spi, out);
}

// Round 4
// 106.772 us; speedup vs baseline: 1.9373x; 1.9373x over previous
//
#include <hip/hip_runtime.h>

#define S_LEN 2048
#define NBATCH 32

typedef __bf16 bf16x8 __attribute__((ext_vector_type(8)));
typedef float f32x4 __attribute__((ext_vector_type(4)));
typedef unsigned short bf_t;   // bf16 storage

__device__ __forceinline__ unsigned short f2bf(float f) {
  __bf16 h = (__bf16)f;
  return __builtin_bit_cast(unsigned short, h);
}

#if __has_builtin(__builtin_amdgcn_global_load_lds)
#define USE_GLL 1
#else
#define USE_GLL 0
#endif

// async global->LDS, 16B per lane. ldsbase must be wave-uniform (HW adds lane*16).
__device__ __forceinline__ void load_lds16(const void* g, void* ldsbase) {
#if USE_GLL
  __builtin_amdgcn_global_load_lds(
      (const __attribute__((address_space(1))) unsigned int*)g,
      (__attribute__((address_space(3))) unsigned int*)ldsbase, 16, 0, 0);
#endif
}

// ---------------------------------------------------------------------------
// x fp32 [B,S,128] -> bf16, 8 elems/thread
__global__ void convert_x(const float* __restrict__ x, bf_t* __restrict__ xb) {
  const size_t i = (size_t)blockIdx.x * blockDim.x + threadIdx.x; // 0..1048575
  const float4 a = ((const float4*)x)[2 * i];
  const float4 c = ((const float4*)x)[2 * i + 1];
  ushort4 o0; o0.x = f2bf(a.x); o0.y = f2bf(a.y); o0.z = f2bf(a.z); o0.w = f2bf(a.w);
  ushort4 o1; o1.x = f2bf(c.x); o1.y = f2bf(c.y); o1.z = f2bf(c.z); o1.w = f2bf(c.w);
  ((ushort4*)xb)[2 * i] = o0;
  ((ushort4*)xb)[2 * i + 1] = o1;
}

// fold conv-bias + BN into per-channel alpha/bias (two layers)
__global__ void fold_bn(const float* __restrict__ b1, const float* __restrict__ g1,
                        const float* __restrict__ be1, const float* __restrict__ m1,
                        const float* __restrict__ v1,
                        const float* __restrict__ b2, const float* __restrict__ g2,
                        const float* __restrict__ be2, const float* __restrict__ m2,
                        const float* __restrict__ v2, float* __restrict__ abuf) {
  int c = threadIdx.x;
  if (c < 256) {
    float a1 = g1[c] * rsqrtf(v1[c] + 1e-5f);
    abuf[c] = a1;
    abuf[256 + c] = (b1[c] - m1[c]) * a1 + be1[c];
    float a2 = g2[c] * rsqrtf(v2[c] + 1e-5f);
    abuf[512 + c] = a2;
    abuf[768 + c] = (b2[c] - m2[c]) * a2 + be2[c];
  }
}

// Weights [256,CIN,TAPS] fp32 -> K-step-major bf16 for the 256co conv kernels:
// offset = tg*8192 + wr*4096 + f*512 + l*8 + j   (elements)
// co = wr*128 + f*16 + (l&15); tg = (cc*TAPS+k)*4+q; ci = cc*128+q*32+(l>>4)*8+j
template <int CIN, int TAPS>
__global__ void prep_w2(const float* __restrict__ w, bf_t* __restrict__ wfm) {
  const int idx = blockIdx.x * 256 + threadIdx.x;
  constexpr int total = 256 * CIN * TAPS;
  if (idx >= total) return;
  const int j = idx & 7;
  const int l = (idx >> 3) & 63;
  const int f = (idx >> 9) & 7;
  const int wr = (idx >> 12) & 1;
  const int tg = idx >> 13;
  const int co = wr * 128 + f * 16 + (l & 15);
  const int cc = tg / (TAPS * 4);
  const int k = (tg / 4) % TAPS;
  const int q = tg & 3;
  const int ci = cc * 128 + q * 32 + (l >> 4) * 8 + j;
  wfm[idx] = f2bf(w[((size_t)co * CIN + ci) * TAPS + k]);
}

// Weights [Cout,Cin,TAPS] fp32 -> fragment-major bf16 (64-co groups, pool kernel)
template <int CIN, int COUT, int TAPS>
__global__ void prep_w(const float* __restrict__ w, bf_t* __restrict__ wfm) {
  constexpr int T = CIN * TAPS / 32;
  const int idx = blockIdx.x * 256 + threadIdx.x;
  constexpr int total = COUT * CIN * TAPS;
  if (idx >= total) return;
  const int j = idx & 7;
  const int l = (idx >> 3) & 63;
  const int f = (idx >> 9) & 3;
  const int gt = idx >> 11;
  const int t = gt % T;
  const int g = gt / T;
  const int co = g * 64 + f * 16 + (l & 15);
  const int cc = t / (TAPS * 4);
  const int k = (t / 4) % TAPS;
  const int q = t & 3;
  const int ci = cc * 128 + q * 32 + (l >> 4) * 8 + j;
  wfm[idx] = f2bf(w[((size_t)co * CIN + ci) * TAPS + k]);
}

// ---------------------------------------------------------------------------
// Fused conv1d(K=TAPS, pad) + BN + ReLU, bf16 MFMA implicit GEMM.
// Block: 512 thr = 8 waves = 2 co-groups(128) x 4 pos-groups(64).
// Block tile: 256co x 256pos. Wave tile: 128co x 64pos, acc[8][4].
// A (weights) staged in LDS 32KB/phase (2 K-steps), DOUBLE-buffered, lane-
// linear (conflict-free). x staged per 128-ci slice, 66.5KB, single-buffered,
// XOR-swizzled (row&7)<<4. One barrier per phase; stage issued post-barrier
// so GLL flight hides under the 64-MFMA compute (T3-minimum recipe).
template <int CIN, int TAPS>
__global__ __launch_bounds__(512, 2)
void conv_bn_relu(const bf_t* __restrict__ xin, const bf_t* __restrict__ wfm,
                  const float* __restrict__ alpha, const float* __restrict__ bias,
                  bf_t* __restrict__ hout) {
  constexpr int CC = CIN / 128;
  constexpr int HALO = (TAPS - 1) / 2;
  constexpr int NROWS = 256 + 2 * HALO;
  constexpr int TCC = TAPS * 4;       // K-steps per 128-ci slice
  constexpr int P = CC * TCC / 2;     // phases (2 K-steps each)
  constexpr int XSL = NROWS * 256;

  __shared__ char smem[65536 + XSL];  // A dbuf 2x32KB | x slice
  char* xsm = smem + 65536;

  const int tid = threadIdx.x;
  const int l = tid & 63;
  const int wv = tid >> 6;   // 0..7
  const int wr = wv >> 2;    // 0..1 : co-group of 128
  const int wn = wv & 3;     // 0..3 : pos-group of 64
  const int b = blockIdx.x >> 3;
  const int s0 = (blockIdx.x & 7) << 8;
  const int l15 = l & 15;
  const int l4 = l >> 4;

  f32x4 acc[8][4] = {};

  auto STAGE_A = [&](int pg) {
    const char* srcw = (const char*)wfm + (size_t)pg * 32768;
    char* ab = smem + (pg & 1) * 32768;
#pragma unroll
    for (int it = 0; it < 4; ++it) {
      const int off = tid * 16 + it * 8192;
#if USE_GLL
      load_lds16(srcw + off, ab + (off - l * 16));
#else
      *(int4*)(ab + off) = *(const int4*)(srcw + off);
#endif
    }
  };

  auto STAGE_X = [&](int cc) {
    const char* src = (const char*)xin + ((size_t)b * S_LEN * CIN + cc * 128) * 2;
    for (int off = tid * 16; off < XSL; off += 512 * 16) {
      const int row = off >> 8;
      const int c = off & 255;
      const int s = s0 - HALO + row;
      const int cs = c ^ ((row & 7) << 4);
      void* lb = (void*)(xsm + (off - l * 16)); // wave-uniform base
      if ((unsigned)s < (unsigned)S_LEN) {
#if USE_GLL
        load_lds16(src + (size_t)s * (CIN * 2) + cs, lb);
#else
        *(int4*)(xsm + off) = *(const int4*)(src + (size_t)s * (CIN * 2) + cs);
#endif
      } else {
        *(int4*)(xsm + off) = make_int4(0, 0, 0, 0);
      }
    }
  };

  // ---- prologue
  STAGE_X(0);
  STAGE_A(0);

#pragma unroll 1
  for (int p = 0; p < P; ++p) {
    __syncthreads();                      // drains prior stages (vmcnt0+lgkm0)
    const int cc = p / (TCC / 2);
    const int kk = p % (TCC / 2);
    if (CC > 1 && p > 0 && kk == 0) {     // ci-slice boundary: restage x
      STAGE_X(cc);
      __syncthreads();
    }
    if (p + 1 < P) STAGE_A(p + 1);        // flight hides under compute
    const char* ab = smem + (p & 1) * 32768 + wr * 8192;

#pragma unroll
    for (int j2 = 0; j2 < 2; ++j2) {
      const int t = kk * 2 + j2;
      const int k = t >> 2;
      const int q = t & 3;
      bf16x8 bfr[4];
#pragma unroll
      for (int fn = 0; fn < 4; ++fn) {
        const int row = wn * 64 + fn * 16 + l15 + k;
        const int cb = q * 64 + l4 * 16;
        bfr[fn] = *(const bf16x8*)(xsm + row * 256 + (cb ^ ((row & 7) << 4)));
      }
#pragma unroll
      for (int f = 0; f < 8; ++f) {
        const bf16x8 afr = *(const bf16x8*)(ab + j2 * 16384 + f * 1024 + l * 16);
#pragma unroll
        for (int n = 0; n < 4; ++n)
          acc[f][n] = __builtin_amdgcn_mfma_f32_16x16x32_bf16(
              afr, bfr[n], acc[f][n], 0, 0, 0);
      }
    }
  }

  // ---- epilogue: y = relu(acc*alpha + bias) -> bf16 [B,S,256]
  const int cobase = wr * 128;
#pragma unroll
  for (int f = 0; f < 8; ++f) {
    const int co0 = cobase + f * 16 + l4 * 4;
    const f32x4 al = *(const f32x4*)(alpha + co0);
    const f32x4 bi = *(const f32x4*)(bias + co0);
#pragma unroll
    for (int n = 0; n < 4; ++n) {
      const int s = s0 + wn * 64 + n * 16 + l15;
      ushort4 pk;
      pk.x = f2bf(fmaxf(acc[f][n][0] * al[0] + bi[0], 0.f));
      pk.y = f2bf(fmaxf(acc[f][n][1] * al[1] + bi[1], 0.f));
      pk.z = f2bf(fmaxf(acc[f][n][2] * al[2] + bi[2], 0.f));
      pk.w = f2bf(fmaxf(acc[f][n][3] * al[3] + bi[3], 0.f));
      *(ushort4*)((char*)hout + ((size_t)(b * S_LEN + s) * 256 + co0) * 2) = pk;
    }
  }
}

// ---------------------------------------------------------------------------
// Final 1x1 conv (256->128) + bias + masked sum-pool -> partials [B][16][128]
__global__ __launch_bounds__(512, 4)
void conv_pool(const bf_t* __restrict__ xin, const bf_t* __restrict__ wfm,
               const float* __restrict__ bfin, const int* __restrict__ spi,
               float* __restrict__ gpart) {
  constexpr int CIN = 256;
  constexpr int T = 8;

  __shared__ char smem[128 * 256];
  __shared__ float red[4][128];

  const int tid = threadIdx.x;
  const int l = tid & 63;
  const int wv = tid >> 6;
  const int wr = wv >> 2;
  const int wn = wv & 3;
  const int nb = blockIdx.x;
  const int b = nb >> 4;
  const int st = nb & 15;
  const int s0 = st << 7;
  const int l15 = l & 15;
  const int l4 = l >> 4;

  f32x4 acc[4][2] = {};
  const bf_t* wbase = wfm + (size_t)wr * (T * 2048);

  for (int cc = 0; cc < 2; ++cc) {
    const char* src = (const char*)xin + ((size_t)b * S_LEN * CIN + cc * 128) * 2;
    for (int off = tid * 16; off < 128 * 256; off += 512 * 16) {
      const int row = off >> 8;
      const int c = off & 255;
      const int cs = c ^ ((row & 7) << 4);
      void* ldsbase = (void*)(smem + (off - l * 16));
#if USE_GLL
      load_lds16(src + (size_t)(s0 + row) * (CIN * 2) + cs, ldsbase);
#else
      *(int4*)(smem + off) = *(const int4*)(src + (size_t)(s0 + row) * (CIN * 2) + cs);
#endif
    }
    __syncthreads();

#pragma unroll
    for (int q = 0; q < 4; ++q) {
      const int t = cc * 4 + q;
      bf16x8 bfr[2];
#pragma unroll
      for (int fn = 0; fn < 2; ++fn) {
        const int row = wn * 32 + fn * 16 + l15;
        const int cb = q * 64 + l4 * 16;
        bfr[fn] = *(const bf16x8*)(smem + row * 256 + (cb ^ ((row & 7) << 4)));
      }
#pragma unroll
      for (int f = 0; f < 4; ++f) {
        const bf16x8 afr =
            *(const bf16x8*)(wbase + ((size_t)(t * 4 + f) * 64 + l) * 8);
        acc[f][0] = __builtin_amdgcn_mfma_f32_16x16x32_bf16(afr, bfr[0], acc[f][0], 0, 0, 0);
        acc[f][1] = __builtin_amdgcn_mfma_f32_16x16x32_bf16(afr, bfr[1], acc[f][1], 0, 0, 0);
      }
    }
    __syncthreads();
  }

  int len = spi[b];
  if (len < 0) len = S_LEN;

#pragma unroll
  for (int f = 0; f < 4; ++f) {
    const int co0 = wr * 64 + f * 16 + l4 * 4;
    const f32x4 bi = *(const f32x4*)(bfin + co0);
    f32x4 vs = {};
#pragma unroll
    for (int fn = 0; fn < 2; ++fn) {
      const int s = s0 + wn * 32 + fn * 16 + l15;
      const float m = (s < len) ? 1.f : 0.f;
      vs[0] += (acc[f][fn][0] + bi[0]) * m;
      vs[1] += (acc[f][fn][1] + bi[1]) * m;
      vs[2] += (acc[f][fn][2] + bi[2]) * m;
      vs[3] += (acc[f][fn][3] + bi[3]) * m;
    }
#pragma unroll
    for (int d = 1; d < 16; d <<= 1) {
      vs[0] += __shfl_xor(vs[0], d, 64);
      vs[1] += __shfl_xor(vs[1], d, 64);
      vs[2] += __shfl_xor(vs[2], d, 64);
      vs[3] += __shfl_xor(vs[3], d, 64);
    }
    if (l15 == 0) {
      red[wn][co0 + 0] = vs[0];
      red[wn][co0 + 1] = vs[1];
      red[wn][co0 + 2] = vs[2];
      red[wn][co0 + 3] = vs[3];
    }
  }
  __syncthreads();
  if (tid < 128) {
    float p = red[0][tid] + red[1][tid] + red[2][tid] + red[3][tid];
    gpart[((size_t)b * 16 + st) * 128 + tid] = p;
  }
}

// pooled[b][d] = sum(partials) / max(len,1)
__global__ void finalize(const float* __restrict__ gpart, const int* __restrict__ spi,
                         float* __restrict__ out) {
  const int b = blockIdx.x;
  const int d = threadIdx.x;
  float s = 0.f;
#pragma unroll
  for (int t = 0; t < 16; ++t) s += gpart[((size_t)b * 16 + t) * 128 + d];
  int len = spi[b];
  if (len < 0) len = S_LEN;
  float denom = (float)(len < 1 ? 1 : len);
  out[b * 128 + d] = s / denom;
}

// ---------------------------------------------------------------------------
extern "C" void kernel_launch(void* const* d_in, const int* in_sizes, int n_in,
                              void* d_out, int out_size, void* d_ws, size_t ws_size,
                              hipStream_t stream) {
  (void)in_sizes; (void)n_in; (void)out_size; (void)ws_size;
  const float* x = (const float*)d_in[0];
  const int* spi = (const int*)d_in[1];
  const float* W1 = (const float*)d_in[2];
  const float* b1 = (const float*)d_in[3];
  const float* g1 = (const float*)d_in[4];
  const float* be1 = (const float*)d_in[5];
  const float* m1 = (const float*)d_in[6];
  const float* v1 = (const float*)d_in[7];
  const float* W2 = (const float*)d_in[8];
  const float* b2 = (const float*)d_in[9];
  const float* g2 = (const float*)d_in[10];
  const float* be2 = (const float*)d_in[11];
  const float* m2 = (const float*)d_in[12];
  const float* v2 = (const float*)d_in[13];
  const float* Wf = (const float*)d_in[14];
  const float* bf_ = (const float*)d_in[15];
  float* out = (float*)d_out;

  char* ws = (char*)d_ws;
  bf_t* xb   = (bf_t*)(ws);                          // 16,777,216 B
  bf_t* h1   = (bf_t*)(ws + 16777216);               // 33,554,432 B
  bf_t* h2   = (bf_t*)(ws + 50331648);               // 33,554,432 B
  bf_t* wf1  = (bf_t*)(ws + 83886080);               //    327,680 B
  bf_t* wf2  = (bf_t*)(ws + 84213760);               //    655,360 B
  bf_t* wff  = (bf_t*)(ws + 84869120);               //     65,536 B
  float* abuf  = (float*)(ws + 84934656);            //      4,096 B
  float* gpart = (float*)(ws + 84938752);            //    262,144 B

  convert_x<<<4096, 256, 0, stream>>>(x, xb);
  fold_bn<<<1, 256, 0, stream>>>(b1, g1, be1, m1, v1, b2, g2, be2, m2, v2, abuf);
  prep_w2<128, 5><<<640, 256, 0, stream>>>(W1, wf1);
  prep_w2<256, 5><<<1280, 256, 0, stream>>>(W2, wf2);
  prep_w<256, 128, 1><<<128, 256, 0, stream>>>(Wf, wff);

  conv_bn_relu<128, 5><<<256, 512, 0, stream>>>(xb, wf1, abuf, abuf + 256, h1);
  conv_bn_relu<256, 5><<<256, 512, 0, stream>>>(h1, wf2, abuf + 512, abuf + 768, h2);
  conv_pool<<<512, 512, 0, stream>>>(h2, wff, bf_, spi, gpart);
  finalize<<<32, 128, 0, stream>>>(gpart, spi, out);
}